// Round 15
// baseline (34.246 us; speedup 1.0000x reference)
//
#include <hip/hip_runtime.h>

#define TT 262144
#define BB 16
#define SS 65536      // TT/4 quads per batch
#define QPB 1024      // output quads per block = 256 threads x 4 consecutive
#define TILEQ 1056    // QPB + 32 halo quads
#define PX(j) ((j) + ((j) >> 2))      // padded physical quad index
#define LDSQ 1320     // PX(1055)+1 = 1319 -> 1320

typedef float floatx16 __attribute__((ext_vector_type(16), aligned(16)));

// ---------------------------------------------------------------------------
// prep_w: build combined filter W (validated rounds 10-14).
//   out[4u+p] = sum_i W[p][i] * x[4u-64+i],  W[p][i] = 4*C_p[126+p-i]
//   Quad form: out-quad u, tap k=0..32: component p uses floats
//   Wg[132p+4k..+3] dotted with x-quad (u-16+k).
// ---------------------------------------------------------------------------
__global__ __launch_bounds__(256) void prep_w(const float* __restrict__ H,
                                              const float* __restrict__ G,
                                              float* __restrict__ W) {
    int t = blockIdx.x * 256 + threadIdx.x;   // 0..2303
    int e = t >> 2;
    int k = t & 3;
    bool valid = (e < 4 * 132);
    float acc = 0.f;
    if (valid) {
        int p = e / 132;
        int i = e % 132;
        int dd = 126 + p - i;                 // valid 0..124
        if (dd >= 0 && dd <= 124) {
            int j0 = (3 - p) & 3;
#pragma unroll
            for (int jj = 0; jj < 16; ++jj) {
                int j = j0 + 4 * jj;
                if (j <= 62) {
                    int a = 124 - j - dd;
                    if (a >= 0 && a <= 62) acc += H[k * 63 + a] * G[k * 63 + j];
                }
            }
        }
    }
    acc += __shfl_xor(acc, 1);
    acc += __shfl_xor(acc, 2);
    if (valid && k == 0) W[e] = 4.0f * acc;
}

// ---------------------------------------------------------------------------
// Fused PQMF: rolled sliding-window, W via s_load_dwordx16 (one 64-B scalar
// load per phase per 4-tap chunk -> 4 SMEM ops per 256 fmacs, 4x fewer
// lockstep SMEM stalls than per-tap dwordx4). Staging loads issued in
// parallel then written to padded LDS. Edges: one quad per block across 32
// blocks/batch (global-x, 16 s-slot shfl reduce, r9-validated math).
// Phase mapping (validated rounds 2/8-14): component p <- Wg[132p+4k..+3].
// ---------------------------------------------------------------------------
__global__ __launch_bounds__(256) void pqmf_fused(const float* __restrict__ x,
                                                  const float* __restrict__ Wg,
                                                  const float* __restrict__ H,
                                                  const float* __restrict__ G,
                                                  float* __restrict__ out) {
    __shared__ float4 xs4[LDSQ];

    const int tid = threadIdx.x;
    const int bx = blockIdx.x;           // 0..63
    const int b = blockIdx.y;
    const int Q0 = bx * QPB;
    const float4* X4 = reinterpret_cast<const float4*>(x + (size_t)b * TT);

    // ---- stage x tile: issue all loads, then write (padded layout) ----
    const int gq0 = Q0 - 16;
    float4 r0, r1, r2, r3, r4;
    if (bx > 0 && bx < 63) {             // interior: windows fully in bounds
        r0 = X4[gq0 + tid];
        r1 = X4[gq0 + tid + 256];
        r2 = X4[gq0 + tid + 512];
        r3 = X4[gq0 + tid + 768];
        if (tid < 32) r4 = X4[gq0 + tid + 1024];
    } else {
        const float4 z = make_float4(0.f, 0.f, 0.f, 0.f);
        int g0 = gq0 + tid, g1 = g0 + 256, g2 = g0 + 512, g3 = g0 + 768, g4 = g0 + 1024;
        r0 = ((unsigned)g0 < (unsigned)SS) ? X4[g0] : z;
        r1 = ((unsigned)g1 < (unsigned)SS) ? X4[g1] : z;
        r2 = ((unsigned)g2 < (unsigned)SS) ? X4[g2] : z;
        r3 = ((unsigned)g3 < (unsigned)SS) ? X4[g3] : z;
        if (tid < 32) r4 = ((unsigned)g4 < (unsigned)SS) ? X4[g4] : z;
    }
    xs4[PX(tid)]       = r0;
    xs4[PX(tid + 256)] = r1;
    xs4[PX(tid + 512)] = r2;
    xs4[PX(tid + 768)] = r3;
    if (tid < 32) xs4[PX(tid + 1024)] = r4;
    __syncthreads();

    // phys index of tile quad (4*tid + j) is 5*tid + j + (j>>2)
    const float4* xp = xs4 + 5 * tid;

    float4 a0 = make_float4(0.f, 0.f, 0.f, 0.f);
    float4 a1 = a0, a2 = a0, a3 = a0;

// tap d (0..3) within a chunk: phase p coeffs = Pp[4d..4d+3]
#define TAPX(d, x0, x1, x2, x3)                                                \
    {                                                                          \
        a0.x = fmaf(P0[4*(d)+3], (x0).w, fmaf(P0[4*(d)+2], (x0).z, fmaf(P0[4*(d)+1], (x0).y, fmaf(P0[4*(d)+0], (x0).x, a0.x)))); \
        a0.y = fmaf(P1[4*(d)+3], (x0).w, fmaf(P1[4*(d)+2], (x0).z, fmaf(P1[4*(d)+1], (x0).y, fmaf(P1[4*(d)+0], (x0).x, a0.y)))); \
        a0.z = fmaf(P2[4*(d)+3], (x0).w, fmaf(P2[4*(d)+2], (x0).z, fmaf(P2[4*(d)+1], (x0).y, fmaf(P2[4*(d)+0], (x0).x, a0.z)))); \
        a0.w = fmaf(P3[4*(d)+3], (x0).w, fmaf(P3[4*(d)+2], (x0).z, fmaf(P3[4*(d)+1], (x0).y, fmaf(P3[4*(d)+0], (x0).x, a0.w)))); \
        a1.x = fmaf(P0[4*(d)+3], (x1).w, fmaf(P0[4*(d)+2], (x1).z, fmaf(P0[4*(d)+1], (x1).y, fmaf(P0[4*(d)+0], (x1).x, a1.x)))); \
        a1.y = fmaf(P1[4*(d)+3], (x1).w, fmaf(P1[4*(d)+2], (x1).z, fmaf(P1[4*(d)+1], (x1).y, fmaf(P1[4*(d)+0], (x1).x, a1.y)))); \
        a1.z = fmaf(P2[4*(d)+3], (x1).w, fmaf(P2[4*(d)+2], (x1).z, fmaf(P2[4*(d)+1], (x1).y, fmaf(P2[4*(d)+0], (x1).x, a1.z)))); \
        a1.w = fmaf(P3[4*(d)+3], (x1).w, fmaf(P3[4*(d)+2], (x1).z, fmaf(P3[4*(d)+1], (x1).y, fmaf(P3[4*(d)+0], (x1).x, a1.w)))); \
        a2.x = fmaf(P0[4*(d)+3], (x2).w, fmaf(P0[4*(d)+2], (x2).z, fmaf(P0[4*(d)+1], (x2).y, fmaf(P0[4*(d)+0], (x2).x, a2.x)))); \
        a2.y = fmaf(P1[4*(d)+3], (x2).w, fmaf(P1[4*(d)+2], (x2).z, fmaf(P1[4*(d)+1], (x2).y, fmaf(P1[4*(d)+0], (x2).x, a2.y)))); \
        a2.z = fmaf(P2[4*(d)+3], (x2).w, fmaf(P2[4*(d)+2], (x2).z, fmaf(P2[4*(d)+1], (x2).y, fmaf(P2[4*(d)+0], (x2).x, a2.z)))); \
        a2.w = fmaf(P3[4*(d)+3], (x2).w, fmaf(P3[4*(d)+2], (x2).z, fmaf(P3[4*(d)+1], (x2).y, fmaf(P3[4*(d)+0], (x2).x, a2.w)))); \
        a3.x = fmaf(P0[4*(d)+3], (x3).w, fmaf(P0[4*(d)+2], (x3).z, fmaf(P0[4*(d)+1], (x3).y, fmaf(P0[4*(d)+0], (x3).x, a3.x)))); \
        a3.y = fmaf(P1[4*(d)+3], (x3).w, fmaf(P1[4*(d)+2], (x3).z, fmaf(P1[4*(d)+1], (x3).y, fmaf(P1[4*(d)+0], (x3).x, a3.y)))); \
        a3.z = fmaf(P2[4*(d)+3], (x3).w, fmaf(P2[4*(d)+2], (x3).z, fmaf(P2[4*(d)+1], (x3).y, fmaf(P2[4*(d)+0], (x3).x, a3.z)))); \
        a3.w = fmaf(P3[4*(d)+3], (x3).w, fmaf(P3[4*(d)+2], (x3).z, fmaf(P3[4*(d)+1], (x3).y, fmaf(P3[4*(d)+0], (x3).x, a3.w)))); \
    }

    // window holds quads (4mm..4mm+3); physical stride 5 per 4 quads
    float4 w0 = xp[0], w1 = xp[1], w2 = xp[2], w3 = xp[3];

#pragma unroll 1
    for (int mm = 0; mm < 8; ++mm) {
        const int k0 = 4 * mm;
        const floatx16 P0 = *reinterpret_cast<const floatx16*>(Wg + 4 * k0);
        const floatx16 P1 = *reinterpret_cast<const floatx16*>(Wg + 132 + 4 * k0);
        const floatx16 P2 = *reinterpret_cast<const floatx16*>(Wg + 264 + 4 * k0);
        const floatx16 P3 = *reinterpret_cast<const floatx16*>(Wg + 396 + 4 * k0);
        const float4* xq = xp + 5 * mm;
        float4 n0 = xq[5];               // quad 4mm+4
        float4 n1 = xq[6];               // quad 4mm+5
        float4 n2 = xq[7];               // quad 4mm+6
        float4 n3 = xq[8];               // quad 4mm+7
        TAPX(0, w0, w1, w2, w3)
        TAPX(1, w1, w2, w3, n0)
        TAPX(2, w2, w3, n0, n1)
        TAPX(3, w3, n0, n1, n2)
        w0 = n0; w1 = n1; w2 = n2; w3 = n3;
    }
#undef TAPX

    {   // tail tap k=32 with window quads 32..35
        const float4 T0 = *reinterpret_cast<const float4*>(Wg + 128);
        const float4 T1 = *reinterpret_cast<const float4*>(Wg + 132 + 128);
        const float4 T2 = *reinterpret_cast<const float4*>(Wg + 264 + 128);
        const float4 T3 = *reinterpret_cast<const float4*>(Wg + 396 + 128);
#define TT4(ar, xv)                                                            \
        ar.x = fmaf(T0.w, (xv).w, fmaf(T0.z, (xv).z, fmaf(T0.y, (xv).y, fmaf(T0.x, (xv).x, ar.x)))); \
        ar.y = fmaf(T1.w, (xv).w, fmaf(T1.z, (xv).z, fmaf(T1.y, (xv).y, fmaf(T1.x, (xv).x, ar.y)))); \
        ar.z = fmaf(T2.w, (xv).w, fmaf(T2.z, (xv).z, fmaf(T2.y, (xv).y, fmaf(T2.x, (xv).x, ar.z)))); \
        ar.w = fmaf(T3.w, (xv).w, fmaf(T3.z, (xv).z, fmaf(T3.y, (xv).y, fmaf(T3.x, (xv).x, ar.w))));
        TT4(a0, w0)
        TT4(a1, w1)
        TT4(a2, w2)
        TT4(a3, w3)
#undef TT4
    }

    float4* ob4 = reinterpret_cast<float4*>(out + (size_t)b * TT);
    const int t0 = tid * 4;
    const int u0 = Q0 + t0;
    if ((unsigned)(u0 - 16) < (unsigned)(SS - 32))     ob4[u0]     = a0;
    if ((unsigned)(u0 + 1 - 16) < (unsigned)(SS - 32)) ob4[u0 + 1] = a1;
    if ((unsigned)(u0 + 2 - 16) < (unsigned)(SS - 32)) ob4[u0 + 2] = a2;
    if ((unsigned)(u0 + 3 - 16) < (unsigned)(SS - 32)) ob4[u0 + 3] = a3;

    // ---- edge quads: ONE per block, spread over 32 blocks/batch ----
    int ue = -1;
    if (bx < 16) ue = bx;                          // lo edge quads 0..15
    else if (bx >= 48) ue = SS - 64 + bx;          // hi edge quads SS-16..SS-1
    if (ue >= 0 && tid < 16) {
        const float* xb = x + (size_t)b * TT;
        const int s = ue - 7 + tid;                // 16 s-slots
        float c0 = 0.f, c1 = 0.f, c2 = 0.f, c3 = 0.f;
        if (s >= 0 && s < SS) {
            const int xbase = 4 * s - 31;
            float s0 = 0.f, s1 = 0.f, s2 = 0.f, s3 = 0.f;
#pragma unroll
            for (int a = 0; a < 63; ++a) {
                int xi = xbase + a;
                float xv = (xi >= 0 && xi < TT) ? xb[xi] : 0.f;
                s0 += xv * H[a];
                s1 += xv * H[63 + a];
                s2 += xv * H[126 + a];
                s3 += xv * H[189 + a];
            }
            const int d4 = 4 * (s - ue);           // -28..32
            {
                int j = d4 + 31;                   // p = 0 (j can be 63)
                if (j <= 62) c0 = s0 * G[j] + s1 * G[63 + j] + s2 * G[126 + j] + s3 * G[189 + j];
            }
            {
                int j = d4 + 30;                   // p = 1, j in [2,62]
                c1 = s0 * G[j] + s1 * G[63 + j] + s2 * G[126 + j] + s3 * G[189 + j];
            }
            {
                int j = d4 + 29;                   // p = 2, j in [1,61]
                c2 = s0 * G[j] + s1 * G[63 + j] + s2 * G[126 + j] + s3 * G[189 + j];
            }
            {
                int j = d4 + 28;                   // p = 3, j in [0,60]
                c3 = s0 * G[j] + s1 * G[63 + j] + s2 * G[126 + j] + s3 * G[189 + j];
            }
        }
#pragma unroll
        for (int m = 8; m >= 1; m >>= 1) {
            c0 += __shfl_xor(c0, m);
            c1 += __shfl_xor(c1, m);
            c2 += __shfl_xor(c2, m);
            c3 += __shfl_xor(c3, m);
        }
        if (tid == 0) {
            float4 v = make_float4(4.f * c0, 4.f * c1, 4.f * c2, 4.f * c3);
            ob4[ue] = v;
        }
    }
}

extern "C" void kernel_launch(void* const* d_in, const int* in_sizes, int n_in,
                              void* d_out, int out_size, void* d_ws, size_t ws_size,
                              hipStream_t stream) {
    const float* x = (const float*)d_in[0];
    const float* H = (const float*)d_in[1];
    const float* G = (const float*)d_in[2];
    float* outp = (float*)d_out;
    float* W = (float*)d_ws;   // 4*132 floats = 2112 B

    hipLaunchKernelGGL(prep_w, dim3(9), dim3(256), 0, stream, H, G, W);
    hipLaunchKernelGGL(pqmf_fused, dim3(SS / QPB, BB), dim3(256), 0, stream,
                       x, W, H, G, outp);
}